// Round 1
// baseline (2681.384 us; speedup 1.0000x reference)
//
#include <hip/hip_runtime.h>

#define U_COUNT 100000
#define I_COUNT 50000
#define DIM     64
#define N_EDGES 3200000
#define BATCH   16384

// One 64-lane wave-group per edge; lane d owns dimension d.
// Fused both directions: reads edge indices once, does
//   out_item[it] += val * x_user[u]   (A^T direction)
//   out_user[u]  += val * x_item[it]  (A  direction)
__global__ __launch_bounds__(256) void spmm_both(
    const float* __restrict__ x_user,   // [U, D] source for A^T
    const float* __restrict__ x_item,   // [I, D] source for A
    const float* __restrict__ edge_vals,
    const int*   __restrict__ edge_user,
    const int*   __restrict__ edge_item,
    float* __restrict__ out_item,       // [I, D] accumulator (pre-zeroed)
    float* __restrict__ out_user)       // [U, D] accumulator (pre-zeroed)
{
    long long tid = (long long)blockIdx.x * blockDim.x + threadIdx.x;
    int e = (int)(tid >> 6);
    int d = (int)(tid & 63);
    if (e >= N_EDGES) return;

    int   u  = edge_user[e];   // uniform within the 64-lane group (L1 broadcast)
    int   it = edge_item[e];
    float v  = edge_vals[e];

    float xu = x_user[(long long)u  * DIM + d];   // coalesced 256B row read
    float xi = x_item[(long long)it * DIM + d];

    atomicAdd(&out_item[(long long)it * DIM + d], v * xu);
    atomicAdd(&out_user[(long long)u  * DIM + d], v * xi);
}

// One 64-lane wave-group per batch element; dot via shfl butterfly.
__global__ __launch_bounds__(256) void score_kernel(
    const float* __restrict__ u0, const float* __restrict__ u1, const float* __restrict__ u2,
    const float* __restrict__ i0, const float* __restrict__ i1, const float* __restrict__ i2,
    const int* __restrict__ user, const int* __restrict__ pos, const int* __restrict__ neg,
    float* __restrict__ out)
{
    int tid = blockIdx.x * blockDim.x + threadIdx.x;
    int b = tid >> 6;
    int d = tid & 63;
    if (b >= BATCH) return;

    int uu = user[b], pp = pos[b], nn = neg[b];
    const float third = 1.0f / 3.0f;

    float uf = (u0[(long long)uu * DIM + d] + u1[(long long)uu * DIM + d] + u2[(long long)uu * DIM + d]) * third;
    float pf = (i0[(long long)pp * DIM + d] + i1[(long long)pp * DIM + d] + i2[(long long)pp * DIM + d]) * third;
    float nf = (i0[(long long)nn * DIM + d] + i1[(long long)nn * DIM + d] + i2[(long long)nn * DIM + d]) * third;

    float ps = uf * pf;
    float ns = uf * nf;
    #pragma unroll
    for (int off = 32; off > 0; off >>= 1) {
        ps += __shfl_xor(ps, off, 64);
        ns += __shfl_xor(ns, off, 64);
    }
    if (d == 0) {
        out[b]         = ps;   // pos_score [B,1]
        out[BATCH + b] = ns;   // neg_score [B,1]
    }
}

extern "C" void kernel_launch(void* const* d_in, const int* in_sizes, int n_in,
                              void* d_out, int out_size, void* d_ws, size_t ws_size,
                              hipStream_t stream) {
    const float* user_emb  = (const float*)d_in[0];
    const float* item_emb  = (const float*)d_in[1];
    const float* edge_vals = (const float*)d_in[2];
    const int*   edge_user = (const int*)d_in[3];
    const int*   edge_item = (const int*)d_in[4];
    const int*   user      = (const int*)d_in[5];
    const int*   pos_item  = (const int*)d_in[6];
    const int*   neg_item  = (const int*)d_in[7];
    float* out = (float*)d_out;

    // Workspace layout (floats): i1 | u1 | i2 | u2  = 76.8 MB total
    float* i1 = (float*)d_ws;
    float* u1 = i1 + (size_t)I_COUNT * DIM;
    float* i2 = u1 + (size_t)U_COUNT * DIM;
    float* u2 = i2 + (size_t)I_COUNT * DIM;
    size_t accum_bytes = ((size_t)I_COUNT + (size_t)U_COUNT) * DIM * 2 * sizeof(float);
    hipMemsetAsync(d_ws, 0, accum_bytes, stream);

    dim3 blk(256);
    // 64 threads per edge -> E/4 blocks of 256
    int edge_blocks = (N_EDGES + 3) / 4;

    // Layer 1: i1 = A^T u0 ; u1 = A i0
    spmm_both<<<edge_blocks, blk, 0, stream>>>(user_emb, item_emb, edge_vals,
                                               edge_user, edge_item, i1, u1);
    // Layer 2: i2 = A^T u1 ; u2 = A i1
    spmm_both<<<edge_blocks, blk, 0, stream>>>(u1, i1, edge_vals,
                                               edge_user, edge_item, i2, u2);

    int score_blocks = (BATCH * 64) / 256;
    score_kernel<<<score_blocks, blk, 0, stream>>>(user_emb, u1, u2,
                                                   item_emb, i1, i2,
                                                   user, pos_item, neg_item, out);
}

// Round 6
// 1352.499 us; speedup vs baseline: 1.9825x; 1.9825x over previous
//
#include <hip/hip_runtime.h>

#define U_COUNT 100000
#define I_COUNT 50000
#define DIM     64
#define N_EDGES 3200000
#define BATCH   16384
#define N_NODES (U_COUNT + I_COUNT)     // 150000
#define SCAN_B  256
#define NBLK    ((N_NODES + SCAN_B - 1) / SCAN_B)   // 586

// ===================== CSR build =====================
// Unified CSR: csr[2*N_EDGES]; row offsets are GLOBAL (scan over all nodes,
// users first). User rows occupy [0, N_EDGES), item rows [N_EDGES, 2*N_EDGES).

__global__ __launch_bounds__(256) void hist_kernel(
    const int* __restrict__ eu, const int* __restrict__ ei, int* __restrict__ deg)
{
    int e = blockIdx.x * blockDim.x + threadIdx.x;
    if (e >= N_EDGES) return;
    atomicAdd(&deg[eu[e]], 1);
    atomicAdd(&deg[U_COUNT + ei[e]], 1);
}

__global__ __launch_bounds__(SCAN_B) void scan1_kernel(
    const int* __restrict__ deg, int* __restrict__ blocksum)
{
    __shared__ int s[SCAN_B];
    int t = threadIdx.x, g = blockIdx.x * SCAN_B + t;
    s[t] = (g < N_NODES) ? deg[g] : 0;
    __syncthreads();
    for (int off = SCAN_B / 2; off > 0; off >>= 1) {
        if (t < off) s[t] += s[t + off];
        __syncthreads();
    }
    if (t == 0) blocksum[blockIdx.x] = s[0];
}

__global__ __launch_bounds__(1024) void scan2_kernel(
    const int* __restrict__ blocksum, int* __restrict__ blockoff)
{
    __shared__ int s[1024];
    int t = threadIdx.x;
    s[t] = (t < NBLK) ? blocksum[t] : 0;
    __syncthreads();
    for (int off = 1; off < 1024; off <<= 1) {
        int v = (t >= off) ? s[t - off] : 0;
        __syncthreads();
        s[t] += v;
        __syncthreads();
    }
    if (t < NBLK) blockoff[t] = s[t] - blocksum[t];   // exclusive block offsets
}

__global__ __launch_bounds__(SCAN_B) void scan3_kernel(
    const int* __restrict__ deg, const int* __restrict__ blockoff,
    int* __restrict__ row_start, int* __restrict__ cursor)
{
    __shared__ int s[SCAN_B];
    int t = threadIdx.x, g = blockIdx.x * SCAN_B + t;
    int v = (g < N_NODES) ? deg[g] : 0;
    s[t] = v;
    __syncthreads();
    for (int off = 1; off < SCAN_B; off <<= 1) {
        int w = (t >= off) ? s[t - off] : 0;
        __syncthreads();
        s[t] += w;
        __syncthreads();
    }
    if (g < N_NODES) {
        int excl = s[t] - v + blockoff[blockIdx.x];
        row_start[g] = excl;
        cursor[g]    = excl;
    }
}

__global__ __launch_bounds__(256) void scatter_kernel(
    const int* __restrict__ eu, const int* __restrict__ ei, const float* __restrict__ ev,
    int* __restrict__ cursor, int2* __restrict__ csr)
{
    int e = blockIdx.x * blockDim.x + threadIdx.x;
    if (e >= N_EDGES) return;
    int   u  = eu[e];
    int   it = ei[e];
    float v  = ev[e];
    int pu = atomicAdd(&cursor[u], 1);            // global offset in [0, N_EDGES)
    csr[pu] = make_int2(it, __float_as_int(v));
    int pi = atomicAdd(&cursor[U_COUNT + it], 1); // global offset in [N_EDGES, 2*N_EDGES)
    csr[pi] = make_int2(u, __float_as_int(v));
}

// ============ pull SpMM: one 64-lane wave per row, no atomics ============
__global__ __launch_bounds__(256) void spmm_pull(
    const int2* __restrict__ list,     // unified csr
    const int*  __restrict__ rstart,   // global offsets (caller adds node base)
    const int*  __restrict__ rend,     // cursor after scatter == row end
    const float* __restrict__ src,
    float* __restrict__ out, int nrows)
{
    int tid = blockIdx.x * blockDim.x + threadIdx.x;
    int r = tid >> 6;
    int d = tid & 63;
    if (r >= nrows) return;
    r = __builtin_amdgcn_readfirstlane(r);          // wave-uniform -> SGPR
    int k   = rstart[r];
    int end = rend[r];
    float acc = 0.f;
    for (; k + 4 <= end; k += 4) {
        int2 e0 = list[k], e1 = list[k + 1], e2 = list[k + 2], e3 = list[k + 3];
        acc = fmaf(__int_as_float(e0.y), src[(size_t)e0.x * DIM + d], acc);
        acc = fmaf(__int_as_float(e1.y), src[(size_t)e1.x * DIM + d], acc);
        acc = fmaf(__int_as_float(e2.y), src[(size_t)e2.x * DIM + d], acc);
        acc = fmaf(__int_as_float(e3.y), src[(size_t)e3.x * DIM + d], acc);
    }
    for (; k < end; ++k) {
        int2 e0 = list[k];
        acc = fmaf(__int_as_float(e0.y), src[(size_t)e0.x * DIM + d], acc);
    }
    out[(size_t)r * DIM + d] = acc;                  // single non-atomic write
}

// ===== fused epilogue: layer-2 rows pulled on demand + score (fast path) =====
__global__ __launch_bounds__(256) void score_fused(
    const float* __restrict__ u0, const float* __restrict__ i0,
    const float* __restrict__ u1, const float* __restrict__ i1,
    const int2* __restrict__ csr,
    const int* __restrict__ urs, const int* __restrict__ ure,   // user rows (global offs)
    const int* __restrict__ irs, const int* __restrict__ ire,   // item rows (global offs)
    const int* __restrict__ user, const int* __restrict__ pos, const int* __restrict__ neg,
    float* __restrict__ out)
{
    int tid = blockIdx.x * blockDim.x + threadIdx.x;
    int b = tid >> 6;
    int d = tid & 63;
    if (b >= BATCH) return;
    int uu = user[b], pp = pos[b], nn = neg[b];

    // u2[uu] = sum val * i1[col]
    float u2v = 0.f;
    for (int k = urs[uu], e = ure[uu]; k < e; ++k) {
        int2 ed = csr[k];
        u2v = fmaf(__int_as_float(ed.y), i1[(size_t)ed.x * DIM + d], u2v);
    }
    // i2[pp] = sum val * u1[col]
    float i2p = 0.f;
    for (int k = irs[pp], e = ire[pp]; k < e; ++k) {
        int2 ed = csr[k];
        i2p = fmaf(__int_as_float(ed.y), u1[(size_t)ed.x * DIM + d], i2p);
    }
    // i2[nn]
    float i2n = 0.f;
    for (int k = irs[nn], e = ire[nn]; k < e; ++k) {
        int2 ed = csr[k];
        i2n = fmaf(__int_as_float(ed.y), u1[(size_t)ed.x * DIM + d], i2n);
    }

    const float third = 1.0f / 3.0f;
    float uf = (u0[(size_t)uu * DIM + d] + u1[(size_t)uu * DIM + d] + u2v) * third;
    float pf = (i0[(size_t)pp * DIM + d] + i1[(size_t)pp * DIM + d] + i2p) * third;
    float nf = (i0[(size_t)nn * DIM + d] + i1[(size_t)nn * DIM + d] + i2n) * third;
    float ps = uf * pf;
    float ns = uf * nf;
    #pragma unroll
    for (int off = 32; off > 0; off >>= 1) {
        ps += __shfl_xor(ps, off, 64);
        ns += __shfl_xor(ns, off, 64);
    }
    if (d == 0) {
        out[b]         = ps;
        out[BATCH + b] = ns;
    }
}

// ===================== fallback (round-1, known-fits) =====================
__global__ __launch_bounds__(256) void spmm_both(
    const float* __restrict__ x_user, const float* __restrict__ x_item,
    const float* __restrict__ edge_vals,
    const int* __restrict__ edge_user, const int* __restrict__ edge_item,
    float* __restrict__ out_item, float* __restrict__ out_user)
{
    long long tid = (long long)blockIdx.x * blockDim.x + threadIdx.x;
    int e = (int)(tid >> 6);
    int d = (int)(tid & 63);
    if (e >= N_EDGES) return;
    int   u  = edge_user[e];
    int   it = edge_item[e];
    float v  = edge_vals[e];
    float xu = x_user[(long long)u  * DIM + d];
    float xi = x_item[(long long)it * DIM + d];
    atomicAdd(&out_item[(long long)it * DIM + d], v * xu);
    atomicAdd(&out_user[(long long)u  * DIM + d], v * xi);
}

__global__ __launch_bounds__(256) void score_kernel(
    const float* __restrict__ u0, const float* __restrict__ u1, const float* __restrict__ u2,
    const float* __restrict__ i0, const float* __restrict__ i1, const float* __restrict__ i2,
    const int* __restrict__ user, const int* __restrict__ pos, const int* __restrict__ neg,
    float* __restrict__ out)
{
    int tid = blockIdx.x * blockDim.x + threadIdx.x;
    int b = tid >> 6;
    int d = tid & 63;
    if (b >= BATCH) return;
    int uu = user[b], pp = pos[b], nn = neg[b];
    const float third = 1.0f / 3.0f;
    float uf = (u0[(size_t)uu * DIM + d] + u1[(size_t)uu * DIM + d] + u2[(size_t)uu * DIM + d]) * third;
    float pf = (i0[(size_t)pp * DIM + d] + i1[(size_t)pp * DIM + d] + i2[(size_t)pp * DIM + d]) * third;
    float nf = (i0[(size_t)nn * DIM + d] + i1[(size_t)nn * DIM + d] + i2[(size_t)nn * DIM + d]) * third;
    float ps = uf * pf;
    float ns = uf * nf;
    #pragma unroll
    for (int off = 32; off > 0; off >>= 1) {
        ps += __shfl_xor(ps, off, 64);
        ns += __shfl_xor(ns, off, 64);
    }
    if (d == 0) {
        out[b]         = ps;
        out[BATCH + b] = ns;
    }
}

extern "C" void kernel_launch(void* const* d_in, const int* in_sizes, int n_in,
                              void* d_out, int out_size, void* d_ws, size_t ws_size,
                              hipStream_t stream) {
    const float* user_emb  = (const float*)d_in[0];
    const float* item_emb  = (const float*)d_in[1];
    const float* edge_vals = (const float*)d_in[2];
    const int*   edge_user = (const int*)d_in[3];
    const int*   edge_item = (const int*)d_in[4];
    const int*   user      = (const int*)d_in[5];
    const int*   pos_item  = (const int*)d_in[6];
    const int*   neg_item  = (const int*)d_in[7];
    float* out = (float*)d_out;

    // ---- fast-path workspace carve (bytes, 256-aligned) ----
    char* ws = (char*)d_ws;
    size_t off = 0;
    auto carve = [&](size_t bytes) { char* p = ws + off; off = (off + bytes + 255) & ~(size_t)255; return p; };
    int*  deg       = (int*) carve((size_t)N_NODES * 4);
    int*  row_start = (int*) carve((size_t)N_NODES * 4);
    int*  cursor    = (int*) carve((size_t)N_NODES * 4);
    int*  blocksum  = (int*) carve((size_t)NBLK * 4);
    int*  blockoff  = (int*) carve((size_t)NBLK * 4);
    int2* csr       = (int2*)carve((size_t)2 * N_EDGES * 8);   // unified, 51.2 MB
    float* i1       = (float*)carve((size_t)I_COUNT * DIM * 4);
    float* u1       = (float*)carve((size_t)U_COUNT * DIM * 4);
    size_t need_fast = off;   // ~91.4 MB

    int edge_blocks = (N_EDGES + 255) / 256;   // 12500

    if (ws_size >= need_fast) {
        // ================= fast path: CSR + pull + fused layer 2 =================
        hipMemsetAsync(deg, 0, (size_t)N_NODES * 4, stream);

        hist_kernel <<<edge_blocks, 256, 0, stream>>>(edge_user, edge_item, deg);
        scan1_kernel<<<NBLK, SCAN_B, 0, stream>>>(deg, blocksum);
        scan2_kernel<<<1, 1024, 0, stream>>>(blocksum, blockoff);
        scan3_kernel<<<NBLK, SCAN_B, 0, stream>>>(deg, blockoff, row_start, cursor);
        scatter_kernel<<<edge_blocks, 256, 0, stream>>>(edge_user, edge_item, edge_vals,
                                                        cursor, csr);
        // after scatter, cursor[r] == row end (global offsets)

        // Layer 1: i1 = A^T u0 (item rows) ; u1 = A i0 (user rows)
        spmm_pull<<<(I_COUNT * 64) / 256, 256, 0, stream>>>(csr, row_start + U_COUNT,
                                                            cursor + U_COUNT, user_emb, i1, I_COUNT);
        spmm_pull<<<(U_COUNT * 64) / 256, 256, 0, stream>>>(csr, row_start, cursor,
                                                            item_emb, u1, U_COUNT);
        // Layer 2 fused into score: pull u2/i2 rows on demand
        score_fused<<<(BATCH * 64) / 256, 256, 0, stream>>>(
            user_emb, item_emb, u1, i1, csr,
            row_start, cursor, row_start + U_COUNT, cursor + U_COUNT,
            user, pos_item, neg_item, out);
    } else {
        // ================= fallback: round-1 push-atomic (fits 76.8 MB) =================
        float* fi1 = (float*)d_ws;
        float* fu1 = fi1 + (size_t)I_COUNT * DIM;
        float* fi2 = fu1 + (size_t)U_COUNT * DIM;
        float* fu2 = fi2 + (size_t)I_COUNT * DIM;
        size_t accum_bytes = ((size_t)I_COUNT + (size_t)U_COUNT) * DIM * 2 * sizeof(float);
        hipMemsetAsync(d_ws, 0, accum_bytes, stream);

        int eb64 = (N_EDGES + 3) / 4;   // 64 threads per edge
        spmm_both<<<eb64, 256, 0, stream>>>(user_emb, item_emb, edge_vals,
                                            edge_user, edge_item, fi1, fu1);
        spmm_both<<<eb64, 256, 0, stream>>>(fu1, fi1, edge_vals,
                                            edge_user, edge_item, fi2, fu2);
        score_kernel<<<(BATCH * 64) / 256, 256, 0, stream>>>(user_emb, fu1, fu2,
                                                             item_emb, fi1, fi2,
                                                             user, pos_item, neg_item, out);
    }
}

// Round 9
// 1149.004 us; speedup vs baseline: 2.3337x; 1.1771x over previous
//
#include <hip/hip_runtime.h>

#define U_COUNT 100000
#define I_COUNT 50000
#define DIM     64
#define N_EDGES 3200000
#define BATCH   16384
#define N_NODES (U_COUNT + I_COUNT)     // 150000
#define SCAN_B  256
#define NBLK    ((N_NODES + SCAN_B - 1) / SCAN_B)   // 586
#define NPASS   8
#define PRANGE  ((N_NODES + NPASS - 1) / NPASS)     // 18750

// ===================== CSR build =====================
// Unified CSR: csr[2*N_EDGES]; row offsets are GLOBAL (scan over all nodes,
// users first). User rows occupy [0, N_EDGES), item rows [N_EDGES, 2*N_EDGES).

__global__ __launch_bounds__(256) void hist_kernel(
    const int* __restrict__ eu, const int* __restrict__ ei, int* __restrict__ deg)
{
    int e = blockIdx.x * blockDim.x + threadIdx.x;
    if (e >= N_EDGES) return;
    atomicAdd(&deg[eu[e]], 1);
    atomicAdd(&deg[U_COUNT + ei[e]], 1);
}

__global__ __launch_bounds__(SCAN_B) void scan1_kernel(
    const int* __restrict__ deg, int* __restrict__ blocksum)
{
    __shared__ int s[SCAN_B];
    int t = threadIdx.x, g = blockIdx.x * SCAN_B + t;
    s[t] = (g < N_NODES) ? deg[g] : 0;
    __syncthreads();
    for (int off = SCAN_B / 2; off > 0; off >>= 1) {
        if (t < off) s[t] += s[t + off];
        __syncthreads();
    }
    if (t == 0) blocksum[blockIdx.x] = s[0];
}

__global__ __launch_bounds__(1024) void scan2_kernel(
    const int* __restrict__ blocksum, int* __restrict__ blockoff)
{
    __shared__ int s[1024];
    int t = threadIdx.x;
    s[t] = (t < NBLK) ? blocksum[t] : 0;
    __syncthreads();
    for (int off = 1; off < 1024; off <<= 1) {
        int v = (t >= off) ? s[t - off] : 0;
        __syncthreads();
        s[t] += v;
        __syncthreads();
    }
    if (t < NBLK) blockoff[t] = s[t] - blocksum[t];   // exclusive block offsets
}

__global__ __launch_bounds__(SCAN_B) void scan3_kernel(
    const int* __restrict__ deg, const int* __restrict__ blockoff,
    int* __restrict__ row_start, int* __restrict__ cursor)
{
    __shared__ int s[SCAN_B];
    int t = threadIdx.x, g = blockIdx.x * SCAN_B + t;
    int v = (g < N_NODES) ? deg[g] : 0;
    s[t] = v;
    __syncthreads();
    for (int off = 1; off < SCAN_B; off <<= 1) {
        int w = (t >= off) ? s[t - off] : 0;
        __syncthreads();
        s[t] += w;
        __syncthreads();
    }
    if (g < N_NODES) {
        int excl = s[t] - v + blockoff[blockIdx.x];
        row_start[g] = excl;
        cursor[g]    = excl;
    }
}

// Range-filtered scatter pass: only destinations in [lo, hi) are written.
// Active CSR window per pass = 51.2MB/NPASS = 6.4MB -> L2/L3-resident, so a
// row's 5-8 lines coalesce before eviction (kills the 7.7x write amplification).
__global__ __launch_bounds__(256) void scatter_pass(
    const int* __restrict__ eu, const int* __restrict__ ei, const float* __restrict__ ev,
    int* __restrict__ cursor, int2* __restrict__ csr, int lo, int hi)
{
    int e = blockIdx.x * blockDim.x + threadIdx.x;
    if (e >= N_EDGES) return;
    int u  = eu[e];
    int it = ei[e];
    int nu = u;             // user-dest node id
    int ni = U_COUNT + it;  // item-dest node id
    bool wu = (nu >= lo) & (nu < hi);
    bool wi = (ni >= lo) & (ni < hi);
    if (wu | wi) {
        float v = ev[e];
        if (wu) {
            int p = atomicAdd(&cursor[nu], 1);
            csr[p] = make_int2(it, __float_as_int(v));
        }
        if (wi) {
            int p = atomicAdd(&cursor[ni], 1);
            csr[p] = make_int2(u, __float_as_int(v));
        }
    }
}

// ============ pull SpMM: one 64-lane wave per row, no atomics ============
// Merged: rows [0, U_COUNT) compute u1 = A i0 (src item_emb);
//         rows [U_COUNT, N_NODES) compute i1 = A^T u0 (src user_emb).
__global__ __launch_bounds__(256) void spmm_pull_all(
    const int2* __restrict__ list,
    const int*  __restrict__ rstart,   // global offsets, length N_NODES
    const int*  __restrict__ rend,
    const float* __restrict__ user_emb,
    const float* __restrict__ item_emb,
    float* __restrict__ u1, float* __restrict__ i1)
{
    int tid = blockIdx.x * blockDim.x + threadIdx.x;
    int r = tid >> 6;
    int d = tid & 63;
    if (r >= N_NODES) return;
    r = __builtin_amdgcn_readfirstlane(r);          // wave-uniform -> SGPR
    const float* src;
    float* dst;
    if (r < U_COUNT) { src = item_emb; dst = &u1[(size_t)r * DIM]; }
    else             { src = user_emb; dst = &i1[(size_t)(r - U_COUNT) * DIM]; }
    int k   = rstart[r];
    int end = rend[r];
    float acc = 0.f;
    for (; k + 4 <= end; k += 4) {
        int2 e0 = list[k], e1 = list[k + 1], e2 = list[k + 2], e3 = list[k + 3];
        acc = fmaf(__int_as_float(e0.y), src[(size_t)e0.x * DIM + d], acc);
        acc = fmaf(__int_as_float(e1.y), src[(size_t)e1.x * DIM + d], acc);
        acc = fmaf(__int_as_float(e2.y), src[(size_t)e2.x * DIM + d], acc);
        acc = fmaf(__int_as_float(e3.y), src[(size_t)e3.x * DIM + d], acc);
    }
    for (; k < end; ++k) {
        int2 e0 = list[k];
        acc = fmaf(__int_as_float(e0.y), src[(size_t)e0.x * DIM + d], acc);
    }
    dst[d] = acc;                                    // single non-atomic write
}

// ===== fused epilogue: layer-2 rows pulled on demand + score (fast path) =====
__global__ __launch_bounds__(256) void score_fused(
    const float* __restrict__ u0, const float* __restrict__ i0,
    const float* __restrict__ u1, const float* __restrict__ i1,
    const int2* __restrict__ csr,
    const int* __restrict__ urs, const int* __restrict__ ure,   // user rows (global offs)
    const int* __restrict__ irs, const int* __restrict__ ire,   // item rows (global offs)
    const int* __restrict__ user, const int* __restrict__ pos, const int* __restrict__ neg,
    float* __restrict__ out)
{
    int tid = blockIdx.x * blockDim.x + threadIdx.x;
    int b = tid >> 6;
    int d = tid & 63;
    if (b >= BATCH) return;
    int uu = user[b], pp = pos[b], nn = neg[b];

    // u2[uu] = sum val * i1[col]
    float u2v = 0.f;
    for (int k = urs[uu], e = ure[uu]; k < e; ++k) {
        int2 ed = csr[k];
        u2v = fmaf(__int_as_float(ed.y), i1[(size_t)ed.x * DIM + d], u2v);
    }
    // i2[pp] = sum val * u1[col]
    float i2p = 0.f;
    for (int k = irs[pp], e = ire[pp]; k < e; ++k) {
        int2 ed = csr[k];
        i2p = fmaf(__int_as_float(ed.y), u1[(size_t)ed.x * DIM + d], i2p);
    }
    // i2[nn]
    float i2n = 0.f;
    for (int k = irs[nn], e = ire[nn]; k < e; ++k) {
        int2 ed = csr[k];
        i2n = fmaf(__int_as_float(ed.y), u1[(size_t)ed.x * DIM + d], i2n);
    }

    const float third = 1.0f / 3.0f;
    float uf = (u0[(size_t)uu * DIM + d] + u1[(size_t)uu * DIM + d] + u2v) * third;
    float pf = (i0[(size_t)pp * DIM + d] + i1[(size_t)pp * DIM + d] + i2p) * third;
    float nf = (i0[(size_t)nn * DIM + d] + i1[(size_t)nn * DIM + d] + i2n) * third;
    float ps = uf * pf;
    float ns = uf * nf;
    #pragma unroll
    for (int off = 32; off > 0; off >>= 1) {
        ps += __shfl_xor(ps, off, 64);
        ns += __shfl_xor(ns, off, 64);
    }
    if (d == 0) {
        out[b]         = ps;
        out[BATCH + b] = ns;
    }
}

// ===================== fallback (round-1, known-fits) =====================
__global__ __launch_bounds__(256) void spmm_both(
    const float* __restrict__ x_user, const float* __restrict__ x_item,
    const float* __restrict__ edge_vals,
    const int* __restrict__ edge_user, const int* __restrict__ edge_item,
    float* __restrict__ out_item, float* __restrict__ out_user)
{
    long long tid = (long long)blockIdx.x * blockDim.x + threadIdx.x;
    int e = (int)(tid >> 6);
    int d = (int)(tid & 63);
    if (e >= N_EDGES) return;
    int   u  = edge_user[e];
    int   it = edge_item[e];
    float v  = edge_vals[e];
    float xu = x_user[(long long)u  * DIM + d];
    float xi = x_item[(long long)it * DIM + d];
    atomicAdd(&out_item[(long long)it * DIM + d], v * xu);
    atomicAdd(&out_user[(long long)u  * DIM + d], v * xi);
}

__global__ __launch_bounds__(256) void score_kernel(
    const float* __restrict__ u0, const float* __restrict__ u1, const float* __restrict__ u2,
    const float* __restrict__ i0, const float* __restrict__ i1, const float* __restrict__ i2,
    const int* __restrict__ user, const int* __restrict__ pos, const int* __restrict__ neg,
    float* __restrict__ out)
{
    int tid = blockIdx.x * blockDim.x + threadIdx.x;
    int b = tid >> 6;
    int d = tid & 63;
    if (b >= BATCH) return;
    int uu = user[b], pp = pos[b], nn = neg[b];
    const float third = 1.0f / 3.0f;
    float uf = (u0[(size_t)uu * DIM + d] + u1[(size_t)uu * DIM + d] + u2[(size_t)uu * DIM + d]) * third;
    float pf = (i0[(size_t)pp * DIM + d] + i1[(size_t)pp * DIM + d] + i2[(size_t)pp * DIM + d]) * third;
    float nf = (i0[(size_t)nn * DIM + d] + i1[(size_t)nn * DIM + d] + i2[(size_t)nn * DIM + d]) * third;
    float ps = uf * pf;
    float ns = uf * nf;
    #pragma unroll
    for (int off = 32; off > 0; off >>= 1) {
        ps += __shfl_xor(ps, off, 64);
        ns += __shfl_xor(ns, off, 64);
    }
    if (d == 0) {
        out[b]         = ps;
        out[BATCH + b] = ns;
    }
}

extern "C" void kernel_launch(void* const* d_in, const int* in_sizes, int n_in,
                              void* d_out, int out_size, void* d_ws, size_t ws_size,
                              hipStream_t stream) {
    const float* user_emb  = (const float*)d_in[0];
    const float* item_emb  = (const float*)d_in[1];
    const float* edge_vals = (const float*)d_in[2];
    const int*   edge_user = (const int*)d_in[3];
    const int*   edge_item = (const int*)d_in[4];
    const int*   user      = (const int*)d_in[5];
    const int*   pos_item  = (const int*)d_in[6];
    const int*   neg_item  = (const int*)d_in[7];
    float* out = (float*)d_out;

    // ---- fast-path workspace carve (bytes, 256-aligned) ----
    char* ws = (char*)d_ws;
    size_t off = 0;
    auto carve = [&](size_t bytes) { char* p = ws + off; off = (off + bytes + 255) & ~(size_t)255; return p; };
    int*  deg       = (int*) carve((size_t)N_NODES * 4);
    int*  row_start = (int*) carve((size_t)N_NODES * 4);
    int*  cursor    = (int*) carve((size_t)N_NODES * 4);
    int*  blocksum  = (int*) carve((size_t)NBLK * 4);
    int*  blockoff  = (int*) carve((size_t)NBLK * 4);
    int2* csr       = (int2*)carve((size_t)2 * N_EDGES * 8);   // unified, 51.2 MB
    float* i1       = (float*)carve((size_t)I_COUNT * DIM * 4);
    float* u1       = (float*)carve((size_t)U_COUNT * DIM * 4);
    size_t need_fast = off;   // ~91.4 MB (proven to fit in round 6)

    int edge_blocks = (N_EDGES + 255) / 256;   // 12500

    if (ws_size >= need_fast) {
        // ================= fast path: CSR + pull + fused layer 2 =================
        hipMemsetAsync(deg, 0, (size_t)N_NODES * 4, stream);

        hist_kernel <<<edge_blocks, 256, 0, stream>>>(edge_user, edge_item, deg);
        scan1_kernel<<<NBLK, SCAN_B, 0, stream>>>(deg, blocksum);
        scan2_kernel<<<1, 1024, 0, stream>>>(blocksum, blockoff);
        scan3_kernel<<<NBLK, SCAN_B, 0, stream>>>(deg, blockoff, row_start, cursor);

        // Range-partitioned scatter: NPASS passes, each writing a 6.4MB CSR window.
        for (int p = 0; p < NPASS; ++p) {
            int lo = p * PRANGE;
            int hi = (p == NPASS - 1) ? N_NODES : lo + PRANGE;
            scatter_pass<<<edge_blocks, 256, 0, stream>>>(edge_user, edge_item, edge_vals,
                                                          cursor, csr, lo, hi);
        }
        // after passes, cursor[r] == row end (global offsets)

        // Layer 1 (both directions in one kernel): u1 = A i0 ; i1 = A^T u0
        spmm_pull_all<<<(N_NODES * 64) / 256, 256, 0, stream>>>(
            csr, row_start, cursor, user_emb, item_emb, u1, i1);

        // Layer 2 fused into score: pull u2/i2 rows on demand
        score_fused<<<(BATCH * 64) / 256, 256, 0, stream>>>(
            user_emb, item_emb, u1, i1, csr,
            row_start, cursor, row_start + U_COUNT, cursor + U_COUNT,
            user, pos_item, neg_item, out);
    } else {
        // ================= fallback: round-1 push-atomic (fits 76.8 MB) =================
        float* fi1 = (float*)d_ws;
        float* fu1 = fi1 + (size_t)I_COUNT * DIM;
        float* fi2 = fu1 + (size_t)U_COUNT * DIM;
        float* fu2 = fi2 + (size_t)I_COUNT * DIM;
        size_t accum_bytes = ((size_t)I_COUNT + (size_t)U_COUNT) * DIM * 2 * sizeof(float);
        hipMemsetAsync(d_ws, 0, accum_bytes, stream);

        int eb64 = (N_EDGES + 3) / 4;   // 64 threads per edge
        spmm_both<<<eb64, 256, 0, stream>>>(user_emb, item_emb, edge_vals,
                                            edge_user, edge_item, fi1, fu1);
        spmm_both<<<eb64, 256, 0, stream>>>(fu1, fi1, edge_vals,
                                            edge_user, edge_item, fi2, fu2);
        score_kernel<<<(BATCH * 64) / 256, 256, 0, stream>>>(user_emb, fu1, fu2,
                                                             item_emb, fi1, fi2,
                                                             user, pos_item, neg_item, out);
    }
}

// Round 10
// 981.710 us; speedup vs baseline: 2.7313x; 1.1704x over previous
//
#include <hip/hip_runtime.h>

#define U_COUNT 100000
#define I_COUNT 50000
#define DIM     64
#define N_EDGES 3200000
#define BATCH   16384
#define N_NODES (U_COUNT + I_COUNT)     // 150000
#define SCAN_B  256
#define NBLK    ((N_NODES + SCAN_B - 1) / SCAN_B)   // 586
#define NPASS   8
#define PRANGE  ((N_NODES + NPASS - 1) / NPASS)     // 18750

// LDS histogram parameters: 5 passes x 30000 bins, u16-packed in u32 LDS.
#define HPASS   5
#define HRANGE  (N_NODES / HPASS)        // 30000 (exact)
#define HWORDS  (HRANGE / 2)             // 15000 words = 60000 B LDS
#define HB      128                      // blocks per hist pass

// ===================== deg via LDS-partial histogram (no global atomics) =====
// Each block builds a private LDS histogram of endpoints in [lo, lo+HRANGE),
// two u16 counters packed per u32 word (block endpoint total 50K; any single
// bin <= 50K < 65536 so the packed low half cannot overflow into the high).
// Partials are written non-atomically; merge_deg sums them into deg.
__global__ __launch_bounds__(256) void hist_lds(
    const int4* __restrict__ eu4, const int4* __restrict__ ei4,
    unsigned int* __restrict__ partial,   // [HB][HWORDS] for this pass
    int lo)
{
    __shared__ unsigned int bins[HWORDS];
    for (int w = threadIdx.x; w < HWORDS; w += 256) bins[w] = 0;
    __syncthreads();

    const int nvec = N_EDGES / 4;
    for (int v = blockIdx.x * 256 + threadIdx.x; v < nvec; v += HB * 256) {
        int4 u  = eu4[v];
        int4 it = ei4[v];
        int n;
        n = u.x - lo;              if ((unsigned)n < (unsigned)HRANGE) atomicAdd(&bins[n >> 1], (n & 1) ? 0x10000u : 1u);
        n = u.y - lo;              if ((unsigned)n < (unsigned)HRANGE) atomicAdd(&bins[n >> 1], (n & 1) ? 0x10000u : 1u);
        n = u.z - lo;              if ((unsigned)n < (unsigned)HRANGE) atomicAdd(&bins[n >> 1], (n & 1) ? 0x10000u : 1u);
        n = u.w - lo;              if ((unsigned)n < (unsigned)HRANGE) atomicAdd(&bins[n >> 1], (n & 1) ? 0x10000u : 1u);
        n = U_COUNT + it.x - lo;   if ((unsigned)n < (unsigned)HRANGE) atomicAdd(&bins[n >> 1], (n & 1) ? 0x10000u : 1u);
        n = U_COUNT + it.y - lo;   if ((unsigned)n < (unsigned)HRANGE) atomicAdd(&bins[n >> 1], (n & 1) ? 0x10000u : 1u);
        n = U_COUNT + it.z - lo;   if ((unsigned)n < (unsigned)HRANGE) atomicAdd(&bins[n >> 1], (n & 1) ? 0x10000u : 1u);
        n = U_COUNT + it.w - lo;   if ((unsigned)n < (unsigned)HRANGE) atomicAdd(&bins[n >> 1], (n & 1) ? 0x10000u : 1u);
    }
    __syncthreads();

    unsigned int* dst = partial + (size_t)blockIdx.x * HWORDS;
    for (int w = threadIdx.x; w < HWORDS; w += 256) dst[w] = bins[w];   // coalesced
}

// deg[node] = sum over HB blocks of the packed partial counters (unpacked sum).
__global__ __launch_bounds__(256) void merge_deg(
    const unsigned int* __restrict__ partial,   // [HPASS][HB][HWORDS]
    int* __restrict__ deg)
{
    int idx = blockIdx.x * blockDim.x + threadIdx.x;   // global word id
    if (idx >= HPASS * HWORDS) return;
    int p = idx / HWORDS;
    int w = idx - p * HWORDS;
    const unsigned int* base = partial + (size_t)p * HB * HWORDS + w;
    unsigned int lo_s = 0, hi_s = 0;
    for (int b = 0; b < HB; ++b) {
        unsigned int v = base[(size_t)b * HWORDS];
        lo_s += v & 0xFFFFu;
        hi_s += v >> 16;
    }
    int node = p * HRANGE + 2 * w;
    deg[node]     = (int)lo_s;
    deg[node + 1] = (int)hi_s;
}

// ===================== scans (unchanged) =====================
__global__ __launch_bounds__(SCAN_B) void scan1_kernel(
    const int* __restrict__ deg, int* __restrict__ blocksum)
{
    __shared__ int s[SCAN_B];
    int t = threadIdx.x, g = blockIdx.x * SCAN_B + t;
    s[t] = (g < N_NODES) ? deg[g] : 0;
    __syncthreads();
    for (int off = SCAN_B / 2; off > 0; off >>= 1) {
        if (t < off) s[t] += s[t + off];
        __syncthreads();
    }
    if (t == 0) blocksum[blockIdx.x] = s[0];
}

__global__ __launch_bounds__(1024) void scan2_kernel(
    const int* __restrict__ blocksum, int* __restrict__ blockoff)
{
    __shared__ int s[1024];
    int t = threadIdx.x;
    s[t] = (t < NBLK) ? blocksum[t] : 0;
    __syncthreads();
    for (int off = 1; off < 1024; off <<= 1) {
        int v = (t >= off) ? s[t - off] : 0;
        __syncthreads();
        s[t] += v;
        __syncthreads();
    }
    if (t < NBLK) blockoff[t] = s[t] - blocksum[t];   // exclusive block offsets
}

__global__ __launch_bounds__(SCAN_B) void scan3_kernel(
    const int* __restrict__ deg, const int* __restrict__ blockoff,
    int* __restrict__ row_start, int* __restrict__ cursor)
{
    __shared__ int s[SCAN_B];
    int t = threadIdx.x, g = blockIdx.x * SCAN_B + t;
    int v = (g < N_NODES) ? deg[g] : 0;
    s[t] = v;
    __syncthreads();
    for (int off = 1; off < SCAN_B; off <<= 1) {
        int w = (t >= off) ? s[t - off] : 0;
        __syncthreads();
        s[t] += w;
        __syncthreads();
    }
    if (g < N_NODES) {
        int excl = s[t] - v + blockoff[blockIdx.x];
        row_start[g] = excl;
        cursor[g]    = excl;
    }
}

// ===================== range-partitioned scatter (unchanged) =====================
__global__ __launch_bounds__(256) void scatter_pass(
    const int* __restrict__ eu, const int* __restrict__ ei, const float* __restrict__ ev,
    int* __restrict__ cursor, int2* __restrict__ csr, int lo, int hi)
{
    int e = blockIdx.x * blockDim.x + threadIdx.x;
    if (e >= N_EDGES) return;
    int u  = eu[e];
    int it = ei[e];
    int nu = u;
    int ni = U_COUNT + it;
    bool wu = (nu >= lo) & (nu < hi);
    bool wi = (ni >= lo) & (ni < hi);
    if (wu | wi) {
        float v = ev[e];
        if (wu) {
            int p = atomicAdd(&cursor[nu], 1);
            csr[p] = make_int2(it, __float_as_int(v));
        }
        if (wi) {
            int p = atomicAdd(&cursor[ni], 1);
            csr[p] = make_int2(u, __float_as_int(v));
        }
    }
}

// ============ pull SpMM (unchanged) ============
__global__ __launch_bounds__(256) void spmm_pull_all(
    const int2* __restrict__ list,
    const int*  __restrict__ rstart,
    const int*  __restrict__ rend,
    const float* __restrict__ user_emb,
    const float* __restrict__ item_emb,
    float* __restrict__ u1, float* __restrict__ i1)
{
    int tid = blockIdx.x * blockDim.x + threadIdx.x;
    int r = tid >> 6;
    int d = tid & 63;
    if (r >= N_NODES) return;
    r = __builtin_amdgcn_readfirstlane(r);
    const float* src;
    float* dst;
    if (r < U_COUNT) { src = item_emb; dst = &u1[(size_t)r * DIM]; }
    else             { src = user_emb; dst = &i1[(size_t)(r - U_COUNT) * DIM]; }
    int k   = rstart[r];
    int end = rend[r];
    float acc = 0.f;
    for (; k + 4 <= end; k += 4) {
        int2 e0 = list[k], e1 = list[k + 1], e2 = list[k + 2], e3 = list[k + 3];
        acc = fmaf(__int_as_float(e0.y), src[(size_t)e0.x * DIM + d], acc);
        acc = fmaf(__int_as_float(e1.y), src[(size_t)e1.x * DIM + d], acc);
        acc = fmaf(__int_as_float(e2.y), src[(size_t)e2.x * DIM + d], acc);
        acc = fmaf(__int_as_float(e3.y), src[(size_t)e3.x * DIM + d], acc);
    }
    for (; k < end; ++k) {
        int2 e0 = list[k];
        acc = fmaf(__int_as_float(e0.y), src[(size_t)e0.x * DIM + d], acc);
    }
    dst[d] = acc;
}

// ===== fused epilogue (unchanged) =====
__global__ __launch_bounds__(256) void score_fused(
    const float* __restrict__ u0, const float* __restrict__ i0,
    const float* __restrict__ u1, const float* __restrict__ i1,
    const int2* __restrict__ csr,
    const int* __restrict__ urs, const int* __restrict__ ure,
    const int* __restrict__ irs, const int* __restrict__ ire,
    const int* __restrict__ user, const int* __restrict__ pos, const int* __restrict__ neg,
    float* __restrict__ out)
{
    int tid = blockIdx.x * blockDim.x + threadIdx.x;
    int b = tid >> 6;
    int d = tid & 63;
    if (b >= BATCH) return;
    int uu = user[b], pp = pos[b], nn = neg[b];

    float u2v = 0.f;
    for (int k = urs[uu], e = ure[uu]; k < e; ++k) {
        int2 ed = csr[k];
        u2v = fmaf(__int_as_float(ed.y), i1[(size_t)ed.x * DIM + d], u2v);
    }
    float i2p = 0.f;
    for (int k = irs[pp], e = ire[pp]; k < e; ++k) {
        int2 ed = csr[k];
        i2p = fmaf(__int_as_float(ed.y), u1[(size_t)ed.x * DIM + d], i2p);
    }
    float i2n = 0.f;
    for (int k = irs[nn], e = ire[nn]; k < e; ++k) {
        int2 ed = csr[k];
        i2n = fmaf(__int_as_float(ed.y), u1[(size_t)ed.x * DIM + d], i2n);
    }

    const float third = 1.0f / 3.0f;
    float uf = (u0[(size_t)uu * DIM + d] + u1[(size_t)uu * DIM + d] + u2v) * third;
    float pf = (i0[(size_t)pp * DIM + d] + i1[(size_t)pp * DIM + d] + i2p) * third;
    float nf = (i0[(size_t)nn * DIM + d] + i1[(size_t)nn * DIM + d] + i2n) * third;
    float ps = uf * pf;
    float ns = uf * nf;
    #pragma unroll
    for (int off = 32; off > 0; off >>= 1) {
        ps += __shfl_xor(ps, off, 64);
        ns += __shfl_xor(ns, off, 64);
    }
    if (d == 0) {
        out[b]         = ps;
        out[BATCH + b] = ns;
    }
}

// ===================== fallback (round-1, known-fits) =====================
__global__ __launch_bounds__(256) void spmm_both(
    const float* __restrict__ x_user, const float* __restrict__ x_item,
    const float* __restrict__ edge_vals,
    const int* __restrict__ edge_user, const int* __restrict__ edge_item,
    float* __restrict__ out_item, float* __restrict__ out_user)
{
    long long tid = (long long)blockIdx.x * blockDim.x + threadIdx.x;
    int e = (int)(tid >> 6);
    int d = (int)(tid & 63);
    if (e >= N_EDGES) return;
    int   u  = edge_user[e];
    int   it = edge_item[e];
    float v  = edge_vals[e];
    float xu = x_user[(long long)u  * DIM + d];
    float xi = x_item[(long long)it * DIM + d];
    atomicAdd(&out_item[(long long)it * DIM + d], v * xu);
    atomicAdd(&out_user[(long long)u  * DIM + d], v * xi);
}

__global__ __launch_bounds__(256) void score_kernel(
    const float* __restrict__ u0, const float* __restrict__ u1, const float* __restrict__ u2,
    const float* __restrict__ i0, const float* __restrict__ i1, const float* __restrict__ i2,
    const int* __restrict__ user, const int* __restrict__ pos, const int* __restrict__ neg,
    float* __restrict__ out)
{
    int tid = blockIdx.x * blockDim.x + threadIdx.x;
    int b = tid >> 6;
    int d = tid & 63;
    if (b >= BATCH) return;
    int uu = user[b], pp = pos[b], nn = neg[b];
    const float third = 1.0f / 3.0f;
    float uf = (u0[(size_t)uu * DIM + d] + u1[(size_t)uu * DIM + d] + u2[(size_t)uu * DIM + d]) * third;
    float pf = (i0[(size_t)pp * DIM + d] + i1[(size_t)pp * DIM + d] + i2[(size_t)pp * DIM + d]) * third;
    float nf = (i0[(size_t)nn * DIM + d] + i1[(size_t)nn * DIM + d] + i2[(size_t)nn * DIM + d]) * third;
    float ps = uf * pf;
    float ns = uf * nf;
    #pragma unroll
    for (int off = 32; off > 0; off >>= 1) {
        ps += __shfl_xor(ps, off, 64);
        ns += __shfl_xor(ns, off, 64);
    }
    if (d == 0) {
        out[b]         = ps;
        out[BATCH + b] = ns;
    }
}

extern "C" void kernel_launch(void* const* d_in, const int* in_sizes, int n_in,
                              void* d_out, int out_size, void* d_ws, size_t ws_size,
                              hipStream_t stream) {
    const float* user_emb  = (const float*)d_in[0];
    const float* item_emb  = (const float*)d_in[1];
    const float* edge_vals = (const float*)d_in[2];
    const int*   edge_user = (const int*)d_in[3];
    const int*   edge_item = (const int*)d_in[4];
    const int*   user      = (const int*)d_in[5];
    const int*   pos_item  = (const int*)d_in[6];
    const int*   neg_item  = (const int*)d_in[7];
    float* out = (float*)d_out;

    // ---- fast-path workspace carve (bytes, 256-aligned) ----
    char* ws = (char*)d_ws;
    size_t off = 0;
    auto carve = [&](size_t bytes) { char* p = ws + off; off = (off + bytes + 255) & ~(size_t)255; return p; };
    int*  deg       = (int*) carve((size_t)N_NODES * 4);
    int*  row_start = (int*) carve((size_t)N_NODES * 4);
    int*  cursor    = (int*) carve((size_t)N_NODES * 4);
    int*  blocksum  = (int*) carve((size_t)NBLK * 4);
    int*  blockoff  = (int*) carve((size_t)NBLK * 4);
    int2* csr       = (int2*)carve((size_t)2 * N_EDGES * 8);   // unified, 51.2 MB
    float* i1       = (float*)carve((size_t)I_COUNT * DIM * 4);
    float* u1       = (float*)carve((size_t)U_COUNT * DIM * 4);
    size_t need_fast = off;   // ~91.4 MB (proven to fit in round 6)

    // hist partials alias the csr region (csr is only written later, by scatter):
    // HPASS * HB * HWORDS * 4 = 38.4 MB <= 51.2 MB.
    unsigned int* partial = (unsigned int*)csr;

    int edge_blocks = (N_EDGES + 255) / 256;   // 12500

    if (ws_size >= need_fast) {
        // ===== deg: LDS-partial histogram, 5 passes, zero global atomics =====
        for (int p = 0; p < HPASS; ++p) {
            hist_lds<<<HB, 256, 0, stream>>>((const int4*)edge_user, (const int4*)edge_item,
                                             partial + (size_t)p * HB * HWORDS, p * HRANGE);
        }
        merge_deg<<<(HPASS * HWORDS + 255) / 256, 256, 0, stream>>>(partial, deg);

        scan1_kernel<<<NBLK, SCAN_B, 0, stream>>>(deg, blocksum);
        scan2_kernel<<<1, 1024, 0, stream>>>(blocksum, blockoff);
        scan3_kernel<<<NBLK, SCAN_B, 0, stream>>>(deg, blockoff, row_start, cursor);

        // Range-partitioned scatter: NPASS passes, each writing a 6.4MB CSR window.
        for (int p = 0; p < NPASS; ++p) {
            int lo = p * PRANGE;
            int hi = (p == NPASS - 1) ? N_NODES : lo + PRANGE;
            scatter_pass<<<edge_blocks, 256, 0, stream>>>(edge_user, edge_item, edge_vals,
                                                          cursor, csr, lo, hi);
        }

        // Layer 1 (both directions): u1 = A i0 ; i1 = A^T u0
        spmm_pull_all<<<(N_NODES * 64) / 256, 256, 0, stream>>>(
            csr, row_start, cursor, user_emb, item_emb, u1, i1);

        // Layer 2 fused into score
        score_fused<<<(BATCH * 64) / 256, 256, 0, stream>>>(
            user_emb, item_emb, u1, i1, csr,
            row_start, cursor, row_start + U_COUNT, cursor + U_COUNT,
            user, pos_item, neg_item, out);
    } else {
        // ================= fallback: round-1 push-atomic =================
        float* fi1 = (float*)d_ws;
        float* fu1 = fi1 + (size_t)I_COUNT * DIM;
        float* fi2 = fu1 + (size_t)U_COUNT * DIM;
        float* fu2 = fi2 + (size_t)I_COUNT * DIM;
        size_t accum_bytes = ((size_t)I_COUNT + (size_t)U_COUNT) * DIM * 2 * sizeof(float);
        hipMemsetAsync(d_ws, 0, accum_bytes, stream);

        int eb64 = (N_EDGES + 3) / 4;
        spmm_both<<<eb64, 256, 0, stream>>>(user_emb, item_emb, edge_vals,
                                            edge_user, edge_item, fi1, fu1);
        spmm_both<<<eb64, 256, 0, stream>>>(fu1, fi1, edge_vals,
                                            edge_user, edge_item, fi2, fu2);
        score_kernel<<<(BATCH * 64) / 256, 256, 0, stream>>>(user_emb, fu1, fu2,
                                                             item_emb, fi1, fi2,
                                                             user, pos_item, neg_item, out);
    }
}